// Round 5
// baseline (227.234 us; speedup 1.0000x reference)
//
#include <hip/hip_runtime.h>

#define NN 50000
#define NE 800000
#define KIN 512
#define HC 128
#define SCAN_NB ((NN + 255) / 256)   // 196

typedef float f32x4 __attribute__((ext_vector_type(4)));
typedef float f32x2 __attribute__((ext_vector_type(2)));
typedef short s16x8 __attribute__((ext_vector_type(8)));

__device__ __forceinline__ ushort f2bf(float f) {
  unsigned u = __float_as_uint(f);
  unsigned r = (u + 0x7FFFu + ((u >> 16) & 1u)) >> 16;  // RNE
  return (ushort)r;
}

// JAX threefry2x32-20, partitionable path: ctr=(0,i), key=(0,42), bits=o0^o1
__device__ __forceinline__ unsigned tf_bits(unsigned i) {
  unsigned x0 = 0u, x1 = i;
  const unsigned ks0 = 0u, ks1 = 42u, ks2 = 0x1BD11BDAu ^ 42u;
  x0 += ks0; x1 += ks1;
#define R(r) { x0 += x1; x1 = (x1 << r) | (x1 >> (32 - r)); x1 ^= x0; }
  R(13) R(15) R(26) R(6)
  x0 += ks1; x1 += ks2 + 1u;
  R(17) R(29) R(16) R(24)
  x0 += ks2; x1 += ks0 + 2u;
  R(13) R(15) R(26) R(6)
  x0 += ks0; x1 += ks1 + 3u;
  R(17) R(29) R(16) R(24)
  x0 += ks1; x1 += ks2 + 4u;
  R(13) R(15) R(26) R(6)
  x0 += ks2; x1 += ks0 + 5u;
#undef R
  return x0 ^ x1;
}

// zero edge-count + W transpose/convert: Wt[c][k] bf16
__global__ void k_prep(const float* __restrict__ W, int* __restrict__ cnt,
                       ushort* __restrict__ Wt) {
  int t = blockIdx.x * 256 + threadIdx.x;   // t < 65536
  if (t < NN) cnt[t] = 0;
  if (t < KIN * HC) {
    int c = t & (HC - 1), k = t >> 7;       // W row-major [k][c]
    Wt[c * KIN + k] = f2bf(W[t]);
  }
}

__global__ void k_cnt(const int* __restrict__ ei, int* __restrict__ cnt) {
  int e = blockIdx.x * 256 + threadIdx.x;
  if (e < NE) atomicAdd(&cnt[ei[NE + e]], 1);
}

// per-block exclusive scan of cnt; off = local exclusive, bsum[b] = block total
__global__ void k_scan1(const int* __restrict__ cnt, int* __restrict__ off,
                        float* __restrict__ dinv, int* __restrict__ bsum) {
  const int i = blockIdx.x * 256 + threadIdx.x;
  const int lane = threadIdx.x & 63, wid = threadIdx.x >> 6;
  int c = (i < NN) ? cnt[i] : 0;
  if (i < NN) dinv[i] = rsqrtf((float)(c + 1));
  int v = c;
#pragma unroll
  for (int d = 1; d < 64; d <<= 1) {
    int t = __shfl_up(v, d);
    if (lane >= d) v += t;
  }
  __shared__ int wsum[4];
  if (lane == 63) wsum[wid] = v;
  __syncthreads();
  int wadd = 0;
#pragma unroll
  for (int w = 0; w < 3; w++) if (w < wid) wadd += wsum[w];
  int incl = v + wadd;
  if (i < NN) off[i] = incl - c;            // block-local exclusive
  if (threadIdx.x == 255) bsum[blockIdx.x] = incl;
}

// exclusive scan of SCAN_NB (<=256) block sums, in place
__global__ void k_scan2(int* __restrict__ bsum) {
  const int t = threadIdx.x;
  const int lane = t & 63, wid = t >> 6;
  int c = (t < SCAN_NB) ? bsum[t] : 0;
  int v = c;
#pragma unroll
  for (int d = 1; d < 64; d <<= 1) {
    int u = __shfl_up(v, d);
    if (lane >= d) v += u;
  }
  __shared__ int wsum[4];
  if (lane == 63) wsum[wid] = v;
  __syncthreads();
  int wadd = 0;
#pragma unroll
  for (int w = 0; w < 3; w++) if (w < wid) wadd += wsum[w];
  if (t < SCAN_NB) bsum[t] = v + wadd - c;  // exclusive
}

__global__ void k_scan3(int* __restrict__ off, const int* __restrict__ bsum) {
  int i = blockIdx.x * 256 + threadIdx.x;
  if (i < NN) off[i] += bsum[blockIdx.x];
  if (i == 0) off[NN] = NE;                 // total degree == NE by construction
}

// csrp[off[dst]+slot] = (bf16(dinv[src])<<16) | src   (src < 65536)
__global__ void k_fill(const int* __restrict__ ei, const int* __restrict__ off,
                       int* __restrict__ cnt, const float* __restrict__ dinv,
                       unsigned* __restrict__ csrp) {
  int e = blockIdx.x * 256 + threadIdx.x;
  if (e >= NE) return;
  int s = ei[e], d = ei[NE + e];
  int slot = atomicAdd(&cnt[d], -1) - 1;
  csrp[off[d] + slot] = ((unsigned)f2bf(dinv[s]) << 16) | (unsigned)s;
}

// x = feats @ W  (bf16 MFMA, f32 acc, bf16 out). One wave owns 16 rows x 128
// cols, no LDS/barriers. Register ping-pong: phase computes K-step i while
// ALL of step i+1's loads (A from HBM, B from L2-resident Wt) are in flight.
__global__ void k_gemm(const float* __restrict__ feats, const ushort* __restrict__ Wt,
                       ushort* __restrict__ xb) {
  const int lane = threadIdx.x & 63;
  const int wid = threadIdx.x >> 6;
  const int r0 = (blockIdx.x * 4 + wid) * 16;
  if (r0 >= NN) return;                     // wave-uniform, no barriers

  f32x4 acc[8];
#pragma unroll
  for (int nt = 0; nt < 8; nt++) acc[nt] = f32x4{0.f, 0.f, 0.f, 0.f};

  int arow = r0 + (lane & 15); if (arow > NN - 1) arow = NN - 1;
  const float*  ap = feats + (size_t)arow * KIN + (lane >> 4) * 8;
  const ushort* bp = Wt + (lane & 15) * KIN + (lane >> 4) * 8;

  f32x4 a0_0, a1_0, a0_1, a1_1;
  s16x8 b_0[8], b_1[8];
  // prologue: fill buffer 0 with K-step 0
  a0_0 = *(const f32x4*)(ap);
  a1_0 = *(const f32x4*)(ap + 4);
#pragma unroll
  for (int nt = 0; nt < 8; nt++) b_0[nt] = *(const s16x8*)(bp + nt * 16 * KIN);

#pragma unroll 1
  for (int ks = 0; ks < KIN; ks += 64) {
    // phase 0: prefetch ks+32 into buf1, compute ks from buf0
    {
      const int kn = ks + 32;               // max 480 < 512, always valid
      a0_1 = *(const f32x4*)(ap + kn);
      a1_1 = *(const f32x4*)(ap + kn + 4);
#pragma unroll
      for (int nt = 0; nt < 8; nt++) b_1[nt] = *(const s16x8*)(bp + nt * 16 * KIN + kn);
      s16x8 af;
#pragma unroll
      for (int t = 0; t < 4; t++) {
        af[t]     = (short)f2bf(a0_0[t]);
        af[t + 4] = (short)f2bf(a1_0[t]);
      }
#pragma unroll
      for (int nt = 0; nt < 8; nt++)
        acc[nt] = __builtin_amdgcn_mfma_f32_16x16x32_bf16(af, b_0[nt], acc[nt], 0, 0, 0);
    }
    // phase 1: prefetch ks+64 into buf0 (clamped dummy on last), compute ks+32
    {
      int kn = ks + 64; if (kn >= KIN) kn = 0;  // harmless dummy reload
      a0_0 = *(const f32x4*)(ap + kn);
      a1_0 = *(const f32x4*)(ap + kn + 4);
#pragma unroll
      for (int nt = 0; nt < 8; nt++) b_0[nt] = *(const s16x8*)(bp + nt * 16 * KIN + kn);
      s16x8 af;
#pragma unroll
      for (int t = 0; t < 4; t++) {
        af[t]     = (short)f2bf(a0_1[t]);
        af[t + 4] = (short)f2bf(a1_1[t]);
      }
#pragma unroll
      for (int nt = 0; nt < 8; nt++)
        acc[nt] = __builtin_amdgcn_mfma_f32_16x16x32_bf16(af, b_1[nt], acc[nt], 0, 0, 0);
    }
  }
  // C/D frag: col = lane&15, row = (lane>>4)*4 + j
  const int rb = r0 + (lane >> 4) * 4;
#pragma unroll
  for (int nt = 0; nt < 8; nt++) {
    int c = nt * 16 + (lane & 15);
#pragma unroll
    for (int j = 0; j < 4; j++) {
      int r = rb + j;
      if (r < NN) xb[(size_t)r * HC + c] = f2bf(acc[nt][j]);
    }
  }
}

// one wave per node: out = dropout(relu(self + sum x[src]*norm + b))
// 2-deep edge software pipeline: csr runs 2 ahead, x-row load 1 ahead.
__global__ void k_agg(const ushort* __restrict__ xb, const float* __restrict__ dinv,
                      const int* __restrict__ off, const unsigned* __restrict__ csrp,
                      const float* __restrict__ b, float* __restrict__ out) {
  int n = blockIdx.x * 4 + (threadIdx.x >> 6);
  if (n >= NN) return;
  const int lane = threadIdx.x & 63;
  const int beg = off[n], end = off[n + 1];
  const int deg = end - beg;
  const float dn = dinv[n];
  f32x2 bb = *(const f32x2*)(b + lane * 2);
  unsigned sw = *(const unsigned*)(xb + (size_t)n * HC + lane * 2);
  float ax = __uint_as_float(sw << 16)         * dn * dn + bb.x;
  float ay = __uint_as_float(sw & 0xFFFF0000u) * dn * dn + bb.y;

  const unsigned* cp = csrp + beg;
  unsigned u0 = (deg > 0) ? cp[0] : 0u;
  unsigned u1 = (deg > 1) ? cp[1] : 0u;
  unsigned w0 = 0u;
  if (deg > 0) w0 = *(const unsigned*)(xb + (size_t)(u0 & 0xFFFFu) * HC + lane * 2);
  for (int j = 0; j < deg; j++) {
    unsigned u2 = (j + 2 < deg) ? cp[j + 2] : 0u;
    unsigned w1 = 0u;
    if (j + 1 < deg)
      w1 = *(const unsigned*)(xb + (size_t)(u1 & 0xFFFFu) * HC + lane * 2);
    float nr = __uint_as_float(u0 & 0xFFFF0000u) * dn;  // bf16(dinv[src]) * dinv[n]
    ax += __uint_as_float(w0 << 16) * nr;
    ay += __uint_as_float(w0 & 0xFFFF0000u) * nr;
    u0 = u1; u1 = u2; w0 = w1;
  }
  int i0 = n * HC + lane * 2;
  float vx = fmaxf(ax, 0.0f) * 2.0f;
  float vy = fmaxf(ay, 0.0f) * 2.0f;
  f32x2 r;
  r.x = (tf_bits((unsigned)i0)     >> 31) ? 0.0f : vx;
  r.y = (tf_bits((unsigned)i0 + 1) >> 31) ? 0.0f : vy;
  *(f32x2*)(out + i0) = r;
}

extern "C" void kernel_launch(void* const* d_in, const int* in_sizes, int n_in,
                              void* d_out, int out_size, void* d_ws, size_t ws_size,
                              hipStream_t stream) {
  const float* feats = (const float*)d_in[0];
  const float* W     = (const float*)d_in[1];
  const float* b     = (const float*)d_in[2];
  const int*   ei    = (const int*)d_in[3];
  float* out = (float*)d_out;

  // ws: xb[NN*HC] bf16 | Wt[HC*KIN] bf16 | dinv[NN] f32 | cnt[NN] i32 |
  //     off[NN+1] i32 | bsum[256] i32 | csrp[NE] u32   (~17 MB)
  char* ws = (char*)d_ws;
  size_t o = 0;
  ushort*   xb   = (ushort*)(ws + o);   o += ((size_t)NN * HC * 2 + 255) & ~(size_t)255;
  ushort*   Wt   = (ushort*)(ws + o);   o += ((size_t)HC * KIN * 2 + 255) & ~(size_t)255;
  float*    dinv = (float*)(ws + o);    o += ((size_t)NN * 4 + 255) & ~(size_t)255;
  int*      cnt  = (int*)(ws + o);      o += ((size_t)NN * 4 + 255) & ~(size_t)255;
  int*      off  = (int*)(ws + o);      o += ((size_t)(NN + 1) * 4 + 255) & ~(size_t)255;
  int*      bsum = (int*)(ws + o);      o += 256 * 4;
  unsigned* csrp = (unsigned*)(ws + o);

  k_prep <<<(KIN * HC + 255) / 256, 256, 0, stream>>>(W, cnt, Wt);
  k_cnt  <<<(NE + 255) / 256, 256, 0, stream>>>(ei, cnt);
  k_scan1<<<SCAN_NB, 256, 0, stream>>>(cnt, off, dinv, bsum);
  k_scan2<<<1, 256, 0, stream>>>(bsum);
  k_scan3<<<SCAN_NB, 256, 0, stream>>>(off, bsum);
  k_fill <<<(NE + 255) / 256, 256, 0, stream>>>(ei, off, cnt, dinv, csrp);
  k_gemm <<<(NN + 63) / 64, 256, 0, stream>>>(feats, Wt, xb);
  k_agg  <<<(NN + 3) / 4, 256, 0, stream>>>(xb, dinv, off, csrp, b, out);
}

// Round 7
// 176.337 us; speedup vs baseline: 1.2886x; 1.2886x over previous
//
#include <hip/hip_runtime.h>

#define NN 50000
#define NE 800000
#define KIN 512
#define HC 128
#define SCAN_NB ((NN + 255) / 256)   // 196

typedef float f32x4 __attribute__((ext_vector_type(4)));
typedef float f32x2 __attribute__((ext_vector_type(2)));
typedef short s16x8 __attribute__((ext_vector_type(8)));

__device__ __forceinline__ ushort f2bf(float f) {
  unsigned u = __float_as_uint(f);
  unsigned r = (u + 0x7FFFu + ((u >> 16) & 1u)) >> 16;  // RNE
  return (ushort)r;
}

// async global->LDS, 16B per lane, dest = wave-uniform base + lane*16
__device__ __forceinline__ void gload_lds16(const void* g, void* l) {
  __builtin_amdgcn_global_load_lds((const __attribute__((address_space(1))) void*)g,
                                   (__attribute__((address_space(3))) void*)l, 16, 0, 0);
}

// JAX threefry2x32-20, partitionable path: ctr=(0,i), key=(0,42), bits=o0^o1
__device__ __forceinline__ unsigned tf_bits(unsigned i) {
  unsigned x0 = 0u, x1 = i;
  const unsigned ks0 = 0u, ks1 = 42u, ks2 = 0x1BD11BDAu ^ 42u;
  x0 += ks0; x1 += ks1;
#define R(r) { x0 += x1; x1 = (x1 << r) | (x1 >> (32 - r)); x1 ^= x0; }
  R(13) R(15) R(26) R(6)
  x0 += ks1; x1 += ks2 + 1u;
  R(17) R(29) R(16) R(24)
  x0 += ks2; x1 += ks0 + 2u;
  R(13) R(15) R(26) R(6)
  x0 += ks0; x1 += ks1 + 3u;
  R(17) R(29) R(16) R(24)
  x0 += ks1; x1 += ks2 + 4u;
  R(13) R(15) R(26) R(6)
  x0 += ks2; x1 += ks0 + 5u;
#undef R
  return x0 ^ x1;
}

// zero edge-count + W transpose/convert: Wt[c][k] bf16
__global__ void k_prep(const float* __restrict__ W, int* __restrict__ cnt,
                       ushort* __restrict__ Wt) {
  int t = blockIdx.x * 256 + threadIdx.x;   // t < 65536
  if (t < NN) cnt[t] = 0;
  if (t < KIN * HC) {
    int c = t & (HC - 1), k = t >> 7;       // W row-major [k][c]
    Wt[c * KIN + k] = f2bf(W[t]);
  }
}

__global__ void k_cnt(const int* __restrict__ ei, int* __restrict__ cnt) {
  int e = blockIdx.x * 256 + threadIdx.x;
  if (e < NE) atomicAdd(&cnt[ei[NE + e]], 1);
}

// per-block exclusive scan of cnt; off = local exclusive, bsum[b] = block total
__global__ void k_scan1(const int* __restrict__ cnt, int* __restrict__ off,
                        float* __restrict__ dinv, int* __restrict__ bsum) {
  const int i = blockIdx.x * 256 + threadIdx.x;
  const int lane = threadIdx.x & 63, wid = threadIdx.x >> 6;
  int c = (i < NN) ? cnt[i] : 0;
  if (i < NN) dinv[i] = rsqrtf((float)(c + 1));
  int v = c;
#pragma unroll
  for (int d = 1; d < 64; d <<= 1) {
    int t = __shfl_up(v, d);
    if (lane >= d) v += t;
  }
  __shared__ int wsum[4];
  if (lane == 63) wsum[wid] = v;
  __syncthreads();
  int wadd = 0;
#pragma unroll
  for (int w = 0; w < 3; w++) if (w < wid) wadd += wsum[w];
  int incl = v + wadd;
  if (i < NN) off[i] = incl - c;            // block-local exclusive
  if (threadIdx.x == 255) bsum[blockIdx.x] = incl;
}

// exclusive scan of SCAN_NB (<=256) block sums, in place
__global__ void k_scan2(int* __restrict__ bsum) {
  const int t = threadIdx.x;
  const int lane = t & 63, wid = t >> 6;
  int c = (t < SCAN_NB) ? bsum[t] : 0;
  int v = c;
#pragma unroll
  for (int d = 1; d < 64; d <<= 1) {
    int u = __shfl_up(v, d);
    if (lane >= d) v += u;
  }
  __shared__ int wsum[4];
  if (lane == 63) wsum[wid] = v;
  __syncthreads();
  int wadd = 0;
#pragma unroll
  for (int w = 0; w < 3; w++) if (w < wid) wadd += wsum[w];
  if (t < SCAN_NB) bsum[t] = v + wadd - c;  // exclusive
}

__global__ void k_scan3(int* __restrict__ off, const int* __restrict__ bsum) {
  int i = blockIdx.x * 256 + threadIdx.x;
  if (i < NN) off[i] += bsum[blockIdx.x];
  if (i == 0) off[NN] = NE;                 // total degree == NE by construction
}

// csrp[off[dst]+slot] = (bf16(dinv[src])<<16) | src   (src < 65536)
__global__ void k_fill(const int* __restrict__ ei, const int* __restrict__ off,
                       int* __restrict__ cnt, const float* __restrict__ dinv,
                       unsigned* __restrict__ csrp) {
  int e = blockIdx.x * 256 + threadIdx.x;
  if (e >= NE) return;
  int s = ei[e], d = ei[NE + e];
  int slot = atomicAdd(&cnt[d], -1) - 1;
  csrp[off[d] + slot] = ((unsigned)f2bf(dinv[s]) << 16) | (unsigned)s;
}

// x = feats @ W  (bf16 MFMA, f32 acc, bf16 out). m97-style: 64x128 tile,
// 4 waves 2x2, single-buffer LDS staged via global_load_lds width=16.
// LDS reads XOR-chunk-swizzled (linear dest + pre-swizzled global source).
__launch_bounds__(256, 4)
__global__ void k_gemm(const float* __restrict__ feats, const ushort* __restrict__ Wt,
                       ushort* __restrict__ xb) {
  __shared__ __align__(16) float  As[64 * 64];    // 16 KB, 256 B/row (16 chunks)
  __shared__ __align__(16) ushort Bs[128 * 64];   // 16 KB, 128 B/row (8 chunks)
  const int tid = threadIdx.x;
  const int lane = tid & 63;
  const int w = tid >> 6;
  const int wm = w >> 1, wn = w & 1;
  const int rbase = blockIdx.x * 64;              // 782 blocks

  f32x4 acc[2][4];
#pragma unroll
  for (int mt = 0; mt < 2; mt++)
#pragma unroll
    for (int nt = 0; nt < 4; nt++) acc[mt][nt] = f32x4{0.f, 0.f, 0.f, 0.f};

  // staging geometry (loop-invariant parts)
  const int a_rt = w * 16 + (lane >> 4);          // + i*4 ; A tile row (lane's own)
  int a_gr[4];
#pragma unroll
  for (int i = 0; i < 4; i++) {
    int gr = rbase + a_rt + i * 4;
    a_gr[i] = (gr < NN) ? gr : NN - 1;
  }
  const int b_ct = w * 32 + (lane >> 3);              // + i*8 ; B tile col (Wt row)
  const int b_ch = ((lane & 7) ^ (b_ct & 7)) << 3;    // bf16 offset of swizzled chunk

  for (int ks = 0; ks < KIN; ks += 64) {
    __syncthreads();                               // prev-step LDS reads done
#pragma unroll
    for (int i = 0; i < 4; i++) {
      // A: wave w stages rows w*16+i*4 .. +3 (1 KB linear).
      // Dest row ar = a_rt + i*4 -> (ar&7) = (a_rt&7) ^ ((i&1)<<2).  [bug fixed]
      int a_ch = ((lane & 15) ^ (a_rt & 7) ^ ((i & 1) << 2)) << 2;   // f32 offset
      gload_lds16(feats + (size_t)a_gr[i] * KIN + ks + a_ch,
                  (char*)As + (w * 16 + i * 4) * 256);
      // B: wave w stages cols w*32+i*8 .. +7 (1 KB linear); i*8 ≡ 0 mod 8.
      gload_lds16(Wt + (size_t)(b_ct + i * 8) * KIN + ks + b_ch,
                  (char*)Bs + (w * 32 + i * 8) * 128);
    }
    __syncthreads();                               // staged (vmcnt drained by barrier)
#pragma unroll
    for (int kk = 0; kk < 2; kk++) {
      s16x8 bfr[4];
#pragma unroll
      for (int nt = 0; nt < 4; nt++) {
        int c = wn * 64 + nt * 16 + (lane & 15);
        int ch = (kk * 4 + (lane >> 4)) ^ (c & 7);
        bfr[nt] = *(const s16x8*)((const char*)Bs + c * 128 + ch * 16);
      }
#pragma unroll
      for (int mt = 0; mt < 2; mt++) {
        int r = wm * 32 + mt * 16 + (lane & 15);
        int c0 = kk * 8 + (lane >> 4) * 2;
        f32x4 f0 = *(const f32x4*)((const char*)As + r * 256 + ((c0 ^ (r & 7)) * 16));
        f32x4 f1 = *(const f32x4*)((const char*)As + r * 256 + (((c0 + 1) ^ (r & 7)) * 16));
        s16x8 af;
#pragma unroll
        for (int t = 0; t < 4; t++) {
          af[t]     = (short)f2bf(f0[t]);
          af[t + 4] = (short)f2bf(f1[t]);
        }
#pragma unroll
        for (int nt = 0; nt < 4; nt++)
          acc[mt][nt] = __builtin_amdgcn_mfma_f32_16x16x32_bf16(af, bfr[nt], acc[mt][nt], 0, 0, 0);
      }
    }
  }
  // C/D frag: col = lane&15, row = (lane>>4)*4 + j
#pragma unroll
  for (int mt = 0; mt < 2; mt++) {
    int rb = rbase + wm * 32 + mt * 16 + (lane >> 4) * 4;
#pragma unroll
    for (int nt = 0; nt < 4; nt++) {
      int c = wn * 64 + nt * 16 + (lane & 15);
#pragma unroll
      for (int j = 0; j < 4; j++) {
        int r = rb + j;
        if (r < NN) xb[(size_t)r * HC + c] = f2bf(acc[mt][nt][j]);
      }
    }
  }
}

// one wave per node: out = dropout(relu(self + sum x[src]*norm + b))
// 2-deep edge software pipeline: csr runs 2 ahead, x-row load 1 ahead.
__global__ void k_agg(const ushort* __restrict__ xb, const float* __restrict__ dinv,
                      const int* __restrict__ off, const unsigned* __restrict__ csrp,
                      const float* __restrict__ b, float* __restrict__ out) {
  int n = blockIdx.x * 4 + (threadIdx.x >> 6);
  if (n >= NN) return;
  const int lane = threadIdx.x & 63;
  const int beg = off[n], end = off[n + 1];
  const int deg = end - beg;
  const float dn = dinv[n];
  f32x2 bb = *(const f32x2*)(b + lane * 2);
  unsigned sw = *(const unsigned*)(xb + (size_t)n * HC + lane * 2);
  float ax = __uint_as_float(sw << 16)         * dn * dn + bb.x;
  float ay = __uint_as_float(sw & 0xFFFF0000u) * dn * dn + bb.y;

  const unsigned* cp = csrp + beg;
  unsigned u0 = (deg > 0) ? cp[0] : 0u;
  unsigned u1 = (deg > 1) ? cp[1] : 0u;
  unsigned w0 = 0u;
  if (deg > 0) w0 = *(const unsigned*)(xb + (size_t)(u0 & 0xFFFFu) * HC + lane * 2);
  for (int j = 0; j < deg; j++) {
    unsigned u2 = (j + 2 < deg) ? cp[j + 2] : 0u;
    unsigned w1 = 0u;
    if (j + 1 < deg)
      w1 = *(const unsigned*)(xb + (size_t)(u1 & 0xFFFFu) * HC + lane * 2);
    float nr = __uint_as_float(u0 & 0xFFFF0000u) * dn;  // bf16(dinv[src]) * dinv[n]
    ax += __uint_as_float(w0 << 16) * nr;
    ay += __uint_as_float(w0 & 0xFFFF0000u) * nr;
    u0 = u1; u1 = u2; w0 = w1;
  }
  int i0 = n * HC + lane * 2;
  float vx = fmaxf(ax, 0.0f) * 2.0f;
  float vy = fmaxf(ay, 0.0f) * 2.0f;
  f32x2 r;
  r.x = (tf_bits((unsigned)i0)     >> 31) ? 0.0f : vx;
  r.y = (tf_bits((unsigned)i0 + 1) >> 31) ? 0.0f : vy;
  *(f32x2*)(out + i0) = r;
}

extern "C" void kernel_launch(void* const* d_in, const int* in_sizes, int n_in,
                              void* d_out, int out_size, void* d_ws, size_t ws_size,
                              hipStream_t stream) {
  const float* feats = (const float*)d_in[0];
  const float* W     = (const float*)d_in[1];
  const float* b     = (const float*)d_in[2];
  const int*   ei    = (const int*)d_in[3];
  float* out = (float*)d_out;

  // ws: xb[NN*HC] bf16 | Wt[HC*KIN] bf16 | dinv[NN] f32 | cnt[NN] i32 |
  //     off[NN+1] i32 | bsum[256] i32 | csrp[NE] u32   (~17 MB)
  char* ws = (char*)d_ws;
  size_t o = 0;
  ushort*   xb   = (ushort*)(ws + o);   o += ((size_t)NN * HC * 2 + 255) & ~(size_t)255;
  ushort*   Wt   = (ushort*)(ws + o);   o += ((size_t)HC * KIN * 2 + 255) & ~(size_t)255;
  float*    dinv = (float*)(ws + o);    o += ((size_t)NN * 4 + 255) & ~(size_t)255;
  int*      cnt  = (int*)(ws + o);      o += ((size_t)NN * 4 + 255) & ~(size_t)255;
  int*      off  = (int*)(ws + o);      o += ((size_t)(NN + 1) * 4 + 255) & ~(size_t)255;
  int*      bsum = (int*)(ws + o);      o += 256 * 4;
  unsigned* csrp = (unsigned*)(ws + o);

  k_prep <<<(KIN * HC + 255) / 256, 256, 0, stream>>>(W, cnt, Wt);
  k_cnt  <<<(NE + 255) / 256, 256, 0, stream>>>(ei, cnt);
  k_scan1<<<SCAN_NB, 256, 0, stream>>>(cnt, off, dinv, bsum);
  k_scan2<<<1, 256, 0, stream>>>(bsum);
  k_scan3<<<SCAN_NB, 256, 0, stream>>>(off, bsum);
  k_fill <<<(NE + 255) / 256, 256, 0, stream>>>(ei, off, cnt, dinv, csrp);
  k_gemm <<<(NN + 63) / 64, 256, 0, stream>>>(feats, Wt, xb);
  k_agg  <<<(NN + 3) / 4, 256, 0, stream>>>(xb, dinv, off, csrp, b, out);
}

// Round 8
// 158.466 us; speedup vs baseline: 1.4340x; 1.1128x over previous
//
#include <hip/hip_runtime.h>

#define NN 50000
#define NE 800000
#define KIN 512
#define HC 128
#define SCAN_NB ((NN + 255) / 256)   // 196

typedef float f32x4 __attribute__((ext_vector_type(4)));
typedef float f32x2 __attribute__((ext_vector_type(2)));
typedef short s16x8 __attribute__((ext_vector_type(8)));

__device__ __forceinline__ ushort f2bf(float f) {
  unsigned u = __float_as_uint(f);
  unsigned r = (u + 0x7FFFu + ((u >> 16) & 1u)) >> 16;  // RNE
  return (ushort)r;
}

// async global->LDS, 16B per lane, dest = wave-uniform base + lane*16
__device__ __forceinline__ void gload_lds16(const void* g, void* l) {
  __builtin_amdgcn_global_load_lds((const __attribute__((address_space(1))) void*)g,
                                   (__attribute__((address_space(3))) void*)l, 16, 0, 0);
}

// JAX threefry2x32-20, partitionable path: ctr=(0,i), key=(0,42), bits=o0^o1
__device__ __forceinline__ unsigned tf_bits(unsigned i) {
  unsigned x0 = 0u, x1 = i;
  const unsigned ks0 = 0u, ks1 = 42u, ks2 = 0x1BD11BDAu ^ 42u;
  x0 += ks0; x1 += ks1;
#define R(r) { x0 += x1; x1 = (x1 << r) | (x1 >> (32 - r)); x1 ^= x0; }
  R(13) R(15) R(26) R(6)
  x0 += ks1; x1 += ks2 + 1u;
  R(17) R(29) R(16) R(24)
  x0 += ks2; x1 += ks0 + 2u;
  R(13) R(15) R(26) R(6)
  x0 += ks0; x1 += ks1 + 3u;
  R(17) R(29) R(16) R(24)
  x0 += ks1; x1 += ks2 + 4u;
  R(13) R(15) R(26) R(6)
  x0 += ks2; x1 += ks0 + 5u;
#undef R
  return x0 ^ x1;
}

// count dst degrees (cnt pre-zeroed by memset) + W transpose/convert
__global__ void k_cntprep(const int* __restrict__ ei, int* __restrict__ cnt,
                          const float* __restrict__ W, ushort* __restrict__ Wt) {
  int t = blockIdx.x * 256 + threadIdx.x;
  if (t < KIN * HC) {
    int c = t & (HC - 1), k = t >> 7;       // W row-major [k][c]
    Wt[c * KIN + k] = f2bf(W[t]);
  }
  if (t < NE) atomicAdd(&cnt[ei[NE + t]], 1);
}

// per-block exclusive scan of cnt; off = block-local exclusive, bsum[b] = total
__global__ void k_scan1(const int* __restrict__ cnt, int* __restrict__ off,
                        float* __restrict__ dinv, int* __restrict__ bsum) {
  const int i = blockIdx.x * 256 + threadIdx.x;
  const int lane = threadIdx.x & 63, wid = threadIdx.x >> 6;
  int c = (i < NN) ? cnt[i] : 0;
  if (i < NN) dinv[i] = rsqrtf((float)(c + 1));
  int v = c;
#pragma unroll
  for (int d = 1; d < 64; d <<= 1) {
    int t = __shfl_up(v, d);
    if (lane >= d) v += t;
  }
  __shared__ int wsum[4];
  if (lane == 63) wsum[wid] = v;
  __syncthreads();
  int wadd = 0;
#pragma unroll
  for (int w = 0; w < 3; w++) if (w < wid) wadd += wsum[w];
  int incl = v + wadd;
  if (i < NN) off[i] = incl - c;            // block-local exclusive
  if (threadIdx.x == 255) bsum[blockIdx.x] = incl;
}

// exclusive scan of SCAN_NB (<=256) block sums, in place; also off[NN]=NE
__global__ void k_scan2(int* __restrict__ bsum, int* __restrict__ off) {
  const int t = threadIdx.x;
  const int lane = t & 63, wid = t >> 6;
  int c = (t < SCAN_NB) ? bsum[t] : 0;
  int v = c;
#pragma unroll
  for (int d = 1; d < 64; d <<= 1) {
    int u = __shfl_up(v, d);
    if (lane >= d) v += u;
  }
  __shared__ int wsum[4];
  if (lane == 63) wsum[wid] = v;
  __syncthreads();
  int wadd = 0;
#pragma unroll
  for (int w = 0; w < 3; w++) if (w < wid) wadd += wsum[w];
  if (t < SCAN_NB) bsum[t] = v + wadd - c;  // exclusive
  if (t == 0) off[NN] = NE;
}

// csrp[off[d]+bsum[d>>8]+slot] = (bf16(dinv[src])<<16) | src   (src < 65536)
__global__ void k_fill(const int* __restrict__ ei, const int* __restrict__ off,
                       const int* __restrict__ bsum, int* __restrict__ cnt,
                       const float* __restrict__ dinv, unsigned* __restrict__ csrp) {
  int e = blockIdx.x * 256 + threadIdx.x;
  if (e >= NE) return;
  int s = ei[e], d = ei[NE + e];
  int slot = atomicAdd(&cnt[d], -1) - 1;    // cnt ends back at 0
  csrp[off[d] + bsum[d >> 8] + slot] = ((unsigned)f2bf(dinv[s]) << 16) | (unsigned)s;
}

// x = feats @ W  (bf16 MFMA, f32 acc, bf16 out). m97-style: 64x128 tile,
// 4 waves 2x2, single-buffer LDS staged via global_load_lds width=16.
// LDS reads XOR-chunk-swizzled (linear dest + pre-swizzled global source).
__launch_bounds__(256, 4)
__global__ void k_gemm(const float* __restrict__ feats, const ushort* __restrict__ Wt,
                       ushort* __restrict__ xb) {
  __shared__ __align__(16) float  As[64 * 64];    // 16 KB, 256 B/row (16 chunks)
  __shared__ __align__(16) ushort Bs[128 * 64];   // 16 KB, 128 B/row (8 chunks)
  const int tid = threadIdx.x;
  const int lane = tid & 63;
  const int w = tid >> 6;
  const int wm = w >> 1, wn = w & 1;
  const int rbase = blockIdx.x * 64;              // 782 blocks

  f32x4 acc[2][4];
#pragma unroll
  for (int mt = 0; mt < 2; mt++)
#pragma unroll
    for (int nt = 0; nt < 4; nt++) acc[mt][nt] = f32x4{0.f, 0.f, 0.f, 0.f};

  const int a_rt = w * 16 + (lane >> 4);          // + i*4 ; A tile row (lane's own)
  int a_gr[4];
#pragma unroll
  for (int i = 0; i < 4; i++) {
    int gr = rbase + a_rt + i * 4;
    a_gr[i] = (gr < NN) ? gr : NN - 1;
  }
  const int b_ct = w * 32 + (lane >> 3);              // + i*8 ; B tile col (Wt row)
  const int b_ch = ((lane & 7) ^ (b_ct & 7)) << 3;    // bf16 offset of swizzled chunk

  for (int ks = 0; ks < KIN; ks += 64) {
    __syncthreads();                               // prev-step LDS reads done
#pragma unroll
    for (int i = 0; i < 4; i++) {
      // A dest row ar = a_rt + i*4 -> (ar&7) = (a_rt&7) ^ ((i&1)<<2)
      int a_ch = ((lane & 15) ^ (a_rt & 7) ^ ((i & 1) << 2)) << 2;   // f32 offset
      gload_lds16(feats + (size_t)a_gr[i] * KIN + ks + a_ch,
                  (char*)As + (w * 16 + i * 4) * 256);
      gload_lds16(Wt + (size_t)(b_ct + i * 8) * KIN + ks + b_ch,
                  (char*)Bs + (w * 32 + i * 8) * 128);
    }
    __syncthreads();                               // staged (vmcnt drained by barrier)
#pragma unroll
    for (int kk = 0; kk < 2; kk++) {
      s16x8 bfr[4];
#pragma unroll
      for (int nt = 0; nt < 4; nt++) {
        int c = wn * 64 + nt * 16 + (lane & 15);
        int ch = (kk * 4 + (lane >> 4)) ^ (c & 7);
        bfr[nt] = *(const s16x8*)((const char*)Bs + c * 128 + ch * 16);
      }
#pragma unroll
      for (int mt = 0; mt < 2; mt++) {
        int r = wm * 32 + mt * 16 + (lane & 15);
        int c0 = kk * 8 + (lane >> 4) * 2;
        f32x4 f0 = *(const f32x4*)((const char*)As + r * 256 + ((c0 ^ (r & 7)) * 16));
        f32x4 f1 = *(const f32x4*)((const char*)As + r * 256 + (((c0 + 1) ^ (r & 7)) * 16));
        s16x8 af;
#pragma unroll
        for (int t = 0; t < 4; t++) {
          af[t]     = (short)f2bf(f0[t]);
          af[t + 4] = (short)f2bf(f1[t]);
        }
#pragma unroll
        for (int nt = 0; nt < 4; nt++)
          acc[mt][nt] = __builtin_amdgcn_mfma_f32_16x16x32_bf16(af, bfr[nt], acc[mt][nt], 0, 0, 0);
      }
    }
  }
  // C/D frag: col = lane&15, row = (lane>>4)*4 + j
#pragma unroll
  for (int mt = 0; mt < 2; mt++) {
    int rb = rbase + wm * 32 + mt * 16 + (lane >> 4) * 4;
#pragma unroll
    for (int nt = 0; nt < 4; nt++) {
      int c = wn * 64 + nt * 16 + (lane & 15);
#pragma unroll
      for (int j = 0; j < 4; j++) {
        int r = rb + j;
        if (r < NN) xb[(size_t)r * HC + c] = f2bf(acc[mt][nt][j]);
      }
    }
  }
}

// one wave per node, pair-processed: half h handles edges 2j+h; each lane
// covers 4 channels (8B gather). Cross-half shfl-reduce at the end.
__global__ void k_agg(const ushort* __restrict__ xb, const float* __restrict__ dinv,
                      const int* __restrict__ off, const int* __restrict__ bsum,
                      const unsigned* __restrict__ csrp,
                      const float* __restrict__ b, float* __restrict__ out) {
  int n = blockIdx.x * 4 + (threadIdx.x >> 6);
  if (n >= NN) return;
  const int lane = threadIdx.x & 63;
  const int h = lane >> 5;            // half: edge parity
  const int q = lane & 31;            // channels q*4 .. q*4+3
  const int beg = off[n] + bsum[n >> 8];
  const int end = off[n + 1] + ((n + 1 < NN) ? bsum[(n + 1) >> 8] : 0);
  const int deg = end - beg;
  const float dn = dinv[n];

  uint2 sv = *(const uint2*)(xb + (size_t)n * HC + q * 4);
  f32x4 bb = *(const f32x4*)(b + q * 4);
  float scale = h ? 0.0f : dn * dn;   // self+bias only in half 0
  float a0 = __uint_as_float(sv.x << 16)         * scale + (h ? 0.f : bb[0]);
  float a1 = __uint_as_float(sv.x & 0xFFFF0000u) * scale + (h ? 0.f : bb[1]);
  float a2 = __uint_as_float(sv.y << 16)         * scale + (h ? 0.f : bb[2]);
  float a3 = __uint_as_float(sv.y & 0xFFFF0000u) * scale + (h ? 0.f : bb[3]);

  const unsigned* cp = csrp + beg;
  const int np = (deg + 1) >> 1;      // pairs
  unsigned uc = 0u;
  if (h < deg) uc = cp[h];            // edge 0*2+h
  uint2 g = *(const uint2*)(xb + (size_t)(uc & 0xFFFFu) * HC + q * 4);
  for (int j = 0; j < np; ++j) {
    int idx = 2 * j + 2 + h;          // next pair's edge for this half
    unsigned ucn = 0u;
    if (idx < deg) ucn = cp[idx];
    uint2 gn = *(const uint2*)(xb + (size_t)(ucn & 0xFFFFu) * HC + q * 4);
    float nr = __uint_as_float(uc & 0xFFFF0000u) * dn;  // bf16(dinv[src])*dinv[n]
    a0 += __uint_as_float(g.x << 16)         * nr;
    a1 += __uint_as_float(g.x & 0xFFFF0000u) * nr;
    a2 += __uint_as_float(g.y << 16)         * nr;
    a3 += __uint_as_float(g.y & 0xFFFF0000u) * nr;
    uc = ucn; g = gn;
  }
  // cross-half totals
  a0 += __shfl(a0, lane ^ 32);
  a1 += __shfl(a1, lane ^ 32);
  a2 += __shfl(a2, lane ^ 32);
  a3 += __shfl(a3, lane ^ 32);
  // half h finalizes channels q*4+2h, q*4+2h+1
  float vx = h ? a2 : a0;
  float vy = h ? a3 : a1;
  vx = fmaxf(vx, 0.f) * 2.f;
  vy = fmaxf(vy, 0.f) * 2.f;
  int i0 = n * HC + q * 4 + 2 * h;
  f32x2 r;
  r.x = (tf_bits((unsigned)i0)     >> 31) ? 0.f : vx;
  r.y = (tf_bits((unsigned)i0 + 1) >> 31) ? 0.f : vy;
  *(f32x2*)(out + i0) = r;
}

extern "C" void kernel_launch(void* const* d_in, const int* in_sizes, int n_in,
                              void* d_out, int out_size, void* d_ws, size_t ws_size,
                              hipStream_t stream) {
  const float* feats = (const float*)d_in[0];
  const float* W     = (const float*)d_in[1];
  const float* b     = (const float*)d_in[2];
  const int*   ei    = (const int*)d_in[3];
  float* out = (float*)d_out;

  // ws: xb[NN*HC] bf16 | Wt[HC*KIN] bf16 | dinv[NN] f32 | cnt[NN] i32 |
  //     off[NN+1] i32 | bsum[256] i32 | csrp[NE] u32   (~17 MB)
  char* ws = (char*)d_ws;
  size_t o = 0;
  ushort*   xb   = (ushort*)(ws + o);   o += ((size_t)NN * HC * 2 + 255) & ~(size_t)255;
  ushort*   Wt   = (ushort*)(ws + o);   o += ((size_t)HC * KIN * 2 + 255) & ~(size_t)255;
  float*    dinv = (float*)(ws + o);    o += ((size_t)NN * 4 + 255) & ~(size_t)255;
  int*      cnt  = (int*)(ws + o);      o += ((size_t)NN * 4 + 255) & ~(size_t)255;
  int*      off  = (int*)(ws + o);      o += ((size_t)(NN + 1) * 4 + 255) & ~(size_t)255;
  int*      bsum = (int*)(ws + o);      o += 256 * 4;
  unsigned* csrp = (unsigned*)(ws + o);

  hipMemsetAsync(cnt, 0, (size_t)NN * 4, stream);
  k_cntprep<<<(NE + 255) / 256, 256, 0, stream>>>(ei, cnt, W, Wt);
  k_scan1<<<SCAN_NB, 256, 0, stream>>>(cnt, off, dinv, bsum);
  k_scan2<<<1, 256, 0, stream>>>(bsum, off);
  k_fill <<<(NE + 255) / 256, 256, 0, stream>>>(ei, off, bsum, cnt, dinv, csrp);
  k_gemm <<<(NN + 63) / 64, 256, 0, stream>>>(feats, Wt, xb);
  k_agg  <<<(NN + 3) / 4, 256, 0, stream>>>(xb, dinv, off, bsum, csrp, b, out);
}